// Round 2
// baseline (1015.279 us; speedup 1.0000x reference)
//
#include <hip/hip_runtime.h>
#include <cstdint>
#include <cstddef>

#define DIMX 1024
#define HID  1536
#define BB   4
#define TT   4096
#define MM   (BB*TT)       // 16384 rows
#define NPROJ (2*HID)      // 3072
#define NC   64            // scan chunks
#define CH   64            // chunk length (NC*CH == TT)

typedef _Float16 f16x8 __attribute__((ext_vector_type(8)));
typedef float    f32x4 __attribute__((ext_vector_type(4)));

#define GLOAD_LDS16(g, l) \
  __builtin_amdgcn_global_load_lds((__attribute__((address_space(1))) const void*)(g), \
                                   (__attribute__((address_space(3))) void*)(l), 16, 0, 0)

// ---------------- convert fp32 -> fp16, 4 elems/thread ----------------
__global__ void k_cvt(const float* __restrict__ in, _Float16* __restrict__ out, long n4) {
  long i = (long)blockIdx.x * blockDim.x + threadIdx.x;
  if (i >= n4) return;
  float4 v = ((const float4*)in)[i];
  union { _Float16 h[4]; uint64_t u; } r;
  r.h[0] = (_Float16)v.x; r.h[1] = (_Float16)v.y;
  r.h[2] = (_Float16)v.z; r.h[3] = (_Float16)v.w;
  ((uint64_t*)out)[i] = r.u;
}

// ---------------- GEMM: C[M,N] = A[M,K] * B[N,K]^T, fp16 in, fused epilogues
// 128x128 tile, BK=64, 4 waves (2x2), each wave 64x64 (4x4 frags of 16x16x32)
// MODE 1: split: col<HID -> gelu -> Ch[M,HID]; col>=HID -> raw fp16 -> Ch2[M,HID]
// MODE 2: alpha = exp(-8*softplus(fl[c])*sigmoid(v+bias[c])) -> Cf[M,N] fp32
// MODE 3: xbeta = sqrt(1-a^2+1e-6)*sigmoid(v+bias[c])*xc -> Ch[M,N] fp16
// MODE 4: plain fp32 store -> Cf
#define BM 128
#define BN 128
#define BKK 64
template<int MODE>
__global__ __launch_bounds__(256) void k_gemm(
    const _Float16* __restrict__ A, const _Float16* __restrict__ B,
    float* __restrict__ Cf, _Float16* __restrict__ Ch, _Float16* __restrict__ Ch2,
    const float* __restrict__ bias, const float* __restrict__ fl,
    const float* __restrict__ alpha_in, const _Float16* __restrict__ xc_in,
    int M, int N, int K)
{
  __shared__ __align__(16) _Float16 sA[BM * BKK];
  __shared__ __align__(16) _Float16 sB[BN * BKK];
  const int wave = threadIdx.x >> 6;
  const int lane = threadIdx.x & 63;
  const int wr = wave >> 1, wc = wave & 1;
  const long rowA = (long)blockIdx.y * BM;
  const long rowB = (long)blockIdx.x * BN;
  const int lr = lane >> 3;          // row within 8-row chunk
  const int lc = (lane & 7) * 8;     // 8 fp16 elems = 16B

  f32x4 acc[4][4] = {};

  const int frow = lane & 15;
  const int fk   = (lane >> 4) * 8;

  for (int kt = 0; kt < K; kt += BKK) {
    #pragma unroll
    for (int i = 0; i < 4; ++i) {
      const int ci = wave * 4 + i;               // 16 chunks of 1KB each
      const _Float16* ga = A + (rowA + ci * 8 + lr) * (long)K + kt + lc;
      const _Float16* gb = B + (rowB + ci * 8 + lr) * (long)K + kt + lc;
      GLOAD_LDS16(ga, &sA[ci * 512]);
      GLOAD_LDS16(gb, &sB[ci * 512]);
    }
    __syncthreads();
    #pragma unroll
    for (int kk = 0; kk < 2; ++kk) {
      f16x8 af[4], bfr[4];
      #pragma unroll
      for (int m = 0; m < 4; ++m)
        af[m] = *(const f16x8*)&sA[(wr * 64 + m * 16 + frow) * BKK + kk * 32 + fk];
      #pragma unroll
      for (int n = 0; n < 4; ++n)
        bfr[n] = *(const f16x8*)&sB[(wc * 64 + n * 16 + frow) * BKK + kk * 32 + fk];
      #pragma unroll
      for (int m = 0; m < 4; ++m)
        #pragma unroll
        for (int n = 0; n < 4; ++n)
          acc[m][n] = __builtin_amdgcn_mfma_f32_16x16x32_f16(af[m], bfr[n], acc[m][n], 0, 0, 0);
    }
    __syncthreads();
  }

  const int crow0 = (lane >> 4) * 4;
  const int ccol  = lane & 15;
  #pragma unroll
  for (int m = 0; m < 4; ++m)
    #pragma unroll
    for (int n = 0; n < 4; ++n) {
      long r0 = rowA + wr * 64 + m * 16 + crow0;
      long c  = rowB + wc * 64 + n * 16 + ccol;
      #pragma unroll
      for (int r = 0; r < 4; ++r) {
        float v = acc[m][n][r];
        long rr = r0 + r;
        if (MODE == 1) {
          if (c < HID) {
            float ge = 0.5f * v * (1.f + erff(v * 0.70710678118654752f));
            Ch[rr * (long)HID + c] = (_Float16)ge;
          } else {
            Ch2[rr * (long)HID + (c - HID)] = (_Float16)v;
          }
        } else if (MODE == 2) {
          float rec = 1.f / (1.f + expf(-(v + bias[c])));
          float sp  = log1pf(expf(fl[c]));
          Cf[rr * (long)N + c] = expf(-8.f * sp * rec);
        } else if (MODE == 3) {
          float inp  = 1.f / (1.f + expf(-(v + bias[c])));
          float a    = alpha_in[rr * (long)N + c];
          float beta = sqrtf(1.f - a * a + 1e-6f);
          Ch[rr * (long)N + c] = (_Float16)(beta * inp * (float)xc_in[rr * (long)N + c]);
        } else {
          Cf[rr * (long)N + c] = v;
        }
      }
    }
}

// ---------------- depthwise causal conv K=4, 8 channels/thread ---------
__global__ void k_conv(const _Float16* __restrict__ xhb, const float* __restrict__ cw,
                       const float* __restrict__ cb, _Float16* __restrict__ xch) {
  long i = (long)blockIdx.x * blockDim.x + threadIdx.x;   // over MM*HID/8
  if (i >= (long)MM * (HID / 8)) return;
  const int hb = (int)(i % (HID / 8));
  const long m = i / (HID / 8);
  const int t = (int)(m % TT);
  const int h0 = hb * 8;
  float acc[8];
  #pragma unroll
  for (int j = 0; j < 8; ++j) acc[j] = cb[h0 + j];
  #pragma unroll
  for (int k = 0; k < 4; ++k) {
    if (t + k - 3 >= 0) {
      f16x8 v = *(const f16x8*)&xhb[(m + k - 3) * (long)HID + h0];
      #pragma unroll
      for (int j = 0; j < 8; ++j) acc[j] += (float)v[j] * cw[(h0 + j) * 4 + k];
    }
  }
  f16x8 o;
  #pragma unroll
  for (int j = 0; j < 8; ++j) o[j] = (_Float16)acc[j];
  *(f16x8*)&xch[m * (long)HID + h0] = o;
}

// ---------------- scan phase 1: per-chunk aggregates -------------------
__global__ void k_scan1(const float* __restrict__ alpha, const _Float16* __restrict__ xbeta,
                        float* __restrict__ Ac, float* __restrict__ Bc) {
  long i = (long)blockIdx.x * blockDim.x + threadIdx.x;   // over BB*NC*HID
  if (i >= (long)BB * NC * HID) return;
  const int h = (int)(i % HID);
  const long bc = i / HID;
  const int c = (int)(bc % NC);
  const int b = (int)(bc / NC);
  const long base = ((long)b * TT + (long)c * CH) * HID + h;
  float A = 1.f, Bv = 0.f;
  for (int t = 0; t < CH; ++t) {
    float a = alpha[base + (long)t * HID];
    float x = (float)xbeta[base + (long)t * HID];
    A *= a;
    Bv = a * Bv + x;
  }
  Ac[i] = A; Bc[i] = Bv;
}

// ---------------- scan phase 2: prefix over chunks ---------------------
__global__ void k_scan2(const float* __restrict__ Ac, const float* __restrict__ Bc,
                        float* __restrict__ carry) {
  int i = blockIdx.x * blockDim.x + threadIdx.x;          // over BB*HID
  if (i >= BB * HID) return;
  const int h = i % HID;
  const int b = i / HID;
  float cv = 0.f;
  for (int c = 0; c < NC; ++c) {
    long idx = ((long)b * NC + c) * HID + h;
    carry[idx] = cv;
    cv = Ac[idx] * cv + Bc[idx];
  }
}

// ---------------- scan phase 3: fix-up, write h over alpha (in place) --
__global__ void k_scan3(float* __restrict__ alpha_h, const _Float16* __restrict__ xbeta,
                        const float* __restrict__ carry) {
  long i = (long)blockIdx.x * blockDim.x + threadIdx.x;   // over BB*NC*HID
  if (i >= (long)BB * NC * HID) return;
  const int h = (int)(i % HID);
  const long bc = i / HID;
  const int c = (int)(bc % NC);
  const int b = (int)(bc / NC);
  const long base = ((long)b * TT + (long)c * CH) * HID + h;
  float hv = carry[i];
  for (int t = 0; t < CH; ++t) {
    long idx = base + (long)t * HID;
    float a = alpha_h[idx];
    float x = (float)xbeta[idx];
    hv = a * hv + x;
    alpha_h[idx] = hv;                 // in place: read-then-write same index
  }
}

// ---------------- vb = geluG * h -> fp16, 8/thread ---------------------
__global__ void k_mul(const _Float16* __restrict__ geluG, const float* __restrict__ hbuf,
                      _Float16* __restrict__ vb) {
  long i = (long)blockIdx.x * blockDim.x + threadIdx.x;   // over MM*HID/8
  if (i >= (long)MM * (HID / 8)) return;
  f16x8 g = ((const f16x8*)geluG)[i];
  float4 h0 = ((const float4*)hbuf)[2 * i];
  float4 h1 = ((const float4*)hbuf)[2 * i + 1];
  f16x8 o;
  o[0] = (_Float16)((float)g[0] * h0.x);
  o[1] = (_Float16)((float)g[1] * h0.y);
  o[2] = (_Float16)((float)g[2] * h0.z);
  o[3] = (_Float16)((float)g[3] * h0.w);
  o[4] = (_Float16)((float)g[4] * h1.x);
  o[5] = (_Float16)((float)g[5] * h1.y);
  o[6] = (_Float16)((float)g[6] * h1.z);
  o[7] = (_Float16)((float)g[7] * h1.w);
  ((f16x8*)vb)[i] = o;
}

extern "C" void kernel_launch(void* const* d_in, const int* in_sizes, int n_in,
                              void* d_out, int out_size, void* d_ws, size_t ws_size,
                              hipStream_t stream) {
  const float* x      = (const float*)d_in[0];
  const float* proj_w = (const float*)d_in[1];
  const float* conv_w = (const float*)d_in[2];
  const float* conv_b = (const float*)d_in[3];
  const float* ip_w   = (const float*)d_in[4];
  const float* ip_b   = (const float*)d_in[5];
  const float* gp_w   = (const float*)d_in[6];
  const float* gp_b   = (const float*)d_in[7];
  const float* fl     = (const float*)d_in[8];
  const float* out_w  = (const float*)d_in[9];
  float* out = (float*)d_out;
  (void)in_sizes; (void)n_in; (void)out_size;

  // ---- workspace layout (246 MB) ----
  const size_t SZ_W     = (size_t)NPROJ * DIMX * 2;       //  6,291,456 (shared weight buf)
  const size_t SZ_MH16  = (size_t)MM * HID * 2;           // 50,331,648
  const size_t SZ_MH32  = (size_t)MM * HID * 4;           // 100,663,296
  const size_t NEED = SZ_W + 3 * SZ_MH16 + SZ_MH32;       // 257,949,696
  if (ws_size < NEED) return;  // diagnostic: clean absmax failure instead of fault

  char* ws = (char*)d_ws;
  _Float16* wbuf  = (_Float16*)(ws);                       // weights (sequential reuse)
  _Float16* geluG = (_Float16*)(ws + SZ_W);                // gelu(gate) fp16
  _Float16* xhb   = (_Float16*)(ws + SZ_W + SZ_MH16);      // xh fp16 -> later xbeta fp16
  _Float16* xch   = (_Float16*)(ws + SZ_W + 2 * SZ_MH16);  // conv out fp16 -> later vb
  float*    alph  = (float*)  (ws + SZ_W + 3 * SZ_MH16);   // alpha fp32 -> later h

  // d_out aliasing: fp16 x (32MB) + scan temps (4.5MB); GEMM4 overwrites all at end
  _Float16* xb    = (_Float16*)d_out;                      // 33,554,432 B
  float*    Ac    = (float*)((char*)d_out + 33554432);
  float*    Bc    = (float*)((char*)d_out + 35127296);
  float*    carry = (float*)((char*)d_out + 36700160);     // ends 38,273,024 < 64MB

  const int THR = 256;
  auto blocks = [&](long n) { return dim3((unsigned)((n + THR - 1) / THR)); };

  // x -> fp16 (into d_out)
  k_cvt<<<blocks((long)MM * DIMX / 4), THR, 0, stream>>>(x, xb, (long)MM * DIMX / 4);

  // GEMM1: [M,3072] = xb @ proj_w^T ; epilogue splits gelu(gate) / xh
  k_cvt<<<blocks((long)NPROJ * DIMX / 4), THR, 0, stream>>>(proj_w, wbuf, (long)NPROJ * DIMX / 4);
  k_gemm<1><<<dim3(NPROJ / BN, MM / BM), 256, 0, stream>>>(
      xb, wbuf, nullptr, geluG, xhb, nullptr, nullptr, nullptr, nullptr, MM, NPROJ, DIMX);

  // conv: xhb -> xch (fp16)
  k_conv<<<blocks((long)MM * (HID / 8)), THR, 0, stream>>>(xhb, conv_w, conv_b, xch);

  // GEMM2: alpha = exp(-8*softplus(fl)*sigmoid(xch@gp_w^T + gp_b))
  k_cvt<<<blocks((long)HID * HID / 4), THR, 0, stream>>>(gp_w, wbuf, (long)HID * HID / 4);
  k_gemm<2><<<dim3(HID / BN, MM / BM), 256, 0, stream>>>(
      xch, wbuf, alph, nullptr, nullptr, gp_b, fl, nullptr, nullptr, MM, HID, HID);

  // GEMM3: xbeta = beta*sigmoid(xch@ip_w^T + ip_b)*xc  -> fp16 into xhb
  k_cvt<<<blocks((long)HID * HID / 4), THR, 0, stream>>>(ip_w, wbuf, (long)HID * HID / 4);
  k_gemm<3><<<dim3(HID / BN, MM / BM), 256, 0, stream>>>(
      xch, wbuf, nullptr, xhb, nullptr, ip_b, nullptr, alph, xch, MM, HID, HID);

  // scan: h overwrites alpha
  k_scan1<<<blocks((long)BB * NC * HID), THR, 0, stream>>>(alph, xhb, Ac, Bc);
  k_scan2<<<blocks(BB * HID), THR, 0, stream>>>(Ac, Bc, carry);
  k_scan3<<<blocks((long)BB * NC * HID), THR, 0, stream>>>(alph, xhb, carry);

  // vb = geluG * h -> fp16 into xch
  k_mul<<<blocks((long)MM * (HID / 8)), THR, 0, stream>>>(geluG, alph, xch);

  // GEMM4: out = vb @ out_w^T (plain fp32)
  k_cvt<<<blocks((long)DIMX * HID / 4), THR, 0, stream>>>(out_w, wbuf, (long)DIMX * HID / 4);
  k_gemm<4><<<dim3(DIMX / BN, MM / BM), 256, 0, stream>>>(
      xch, wbuf, out, nullptr, nullptr, nullptr, nullptr, nullptr, nullptr, MM, DIMX, HID);
}

// Round 3
// 914.886 us; speedup vs baseline: 1.1097x; 1.1097x over previous
//
#include <hip/hip_runtime.h>
#include <cstdint>
#include <cstddef>

#define DIMX 1024
#define HID  1536
#define BB   4
#define TT   4096
#define MM   (BB*TT)       // 16384 rows
#define NPROJ (2*HID)      // 3072
#define NC   64            // scan chunks
#define CH   64            // chunk length (NC*CH == TT)

typedef _Float16 f16x8 __attribute__((ext_vector_type(8)));
typedef float    f32x4 __attribute__((ext_vector_type(4)));

#define GLOAD_LDS16(g, l) \
  __builtin_amdgcn_global_load_lds((__attribute__((address_space(1))) const void*)(g), \
                                   (__attribute__((address_space(3))) void*)(l), 16, 0, 0)

__device__ __forceinline__ float fast_sigmoid(float z) {
  return 1.f / (1.f + __expf(-z));
}
__device__ __forceinline__ float fast_erf(float x) {
  float ax = fabsf(x);
  float t = 1.f / (1.f + 0.3275911f * ax);
  float p = t * (0.254829592f + t * (-0.284496736f + t * (1.421413741f +
            t * (-1.453152027f + t * 1.061405429f))));
  float r = 1.f - p * __expf(-ax * ax);
  return copysignf(r, x);
}

// ---------------- convert fp32 -> fp16, 4 elems/thread ----------------
__global__ void k_cvt(const float* __restrict__ in, _Float16* __restrict__ out, long n4) {
  long i = (long)blockIdx.x * blockDim.x + threadIdx.x;
  if (i >= n4) return;
  float4 v = ((const float4*)in)[i];
  union { _Float16 h[4]; uint64_t u; } r;
  r.h[0] = (_Float16)v.x; r.h[1] = (_Float16)v.y;
  r.h[2] = (_Float16)v.z; r.h[3] = (_Float16)v.w;
  ((uint64_t*)out)[i] = r.u;
}

// ---------------- GEMM: C[M,N] = A[M,K] * B[N,K]^T, fp16 in ----------
// 128x256 tile, BK=64, 8 waves (2M x 4N), wave = 64x64 out (4x4 frags).
// Triple-buffered LDS, 2-deep global_load_lds prefetch, counted vmcnt(6),
// raw s_barrier (1 per K-tile), setprio around MFMA, XCD swizzle.
// MODE 1: col<HID -> gelu -> Ch[M,HID]; col>=HID -> raw fp16 -> Ch2[M,HID]
// MODE 2: s = 8*softplus(fl[c])*sigmoid(v+bias[c]) -> Ch fp16 [M,N]
// MODE 3: xbeta = sqrt(1-a^2+1e-6)*sigmoid(v+bias[c])*xc, a=exp(-s) -> Ch fp16
// MODE 4: plain fp32 -> Cf
#define BM 128
#define BN 256
#define BK 64

__device__ __forceinline__ void stage_tile(
    const _Float16* __restrict__ A, const _Float16* __restrict__ B,
    _Float16* sAbuf, _Float16* sBbuf,
    long rowA, long rowB, int kt, int K, int wave, int lane)
{
  const int r8 = lane >> 3;            // 0..7
  const int c8 = (lane & 7) * 8;       // col (fp16 elems), 16B granule
  #pragma unroll
  for (int j = 0; j < 2; ++j) {
    const int ck = wave + 8 * j;       // A chunks 0..15 (8 rows each)
    const _Float16* g = A + (rowA + ck * 8 + r8) * (long)K + kt + c8;
    GLOAD_LDS16(g, sAbuf + ck * 512);
  }
  #pragma unroll
  for (int j = 0; j < 4; ++j) {
    const int ck = wave + 8 * j;       // B chunks 0..31
    const _Float16* g = B + (rowB + ck * 8 + r8) * (long)K + kt + c8;
    GLOAD_LDS16(g, sBbuf + ck * 512);
  }
}

template<int MODE>
__global__ __launch_bounds__(512) void k_gemm(
    const _Float16* __restrict__ A, const _Float16* __restrict__ B,
    float* __restrict__ Cf, _Float16* __restrict__ Ch, _Float16* __restrict__ Ch2,
    const float* __restrict__ bias, const float* __restrict__ fl,
    const _Float16* __restrict__ Sin, const _Float16* __restrict__ xc_in,
    int M, int N, int K, int gridN)
{
  __shared__ __align__(16) _Float16 sA[3][BM * BK];   // 3 x 16 KB
  __shared__ __align__(16) _Float16 sB[3][BN * BK];   // 3 x 32 KB  (total 144 KB)
  const int tid  = threadIdx.x;
  const int wave = tid >> 6;
  const int lane = tid & 63;
  const int wr = wave >> 2, wc = wave & 3;

  // bijective XCD swizzle (gridDim.x % 8 == 0 for all our shapes)
  const int nwg = gridDim.x;
  const int bid = blockIdx.x;
  const int swz = (bid & 7) * (nwg >> 3) + (bid >> 3);
  const long rowA = (long)(swz / gridN) * BM;
  const long rowB = (long)(swz % gridN) * BN;

  const int nt = K / BK;

  stage_tile(A, B, sA[0], sB[0], rowA, rowB, 0,  K, wave, lane);
  stage_tile(A, B, sA[1], sB[1], rowA, rowB, BK, K, wave, lane);
  asm volatile("s_waitcnt vmcnt(6)" ::: "memory");   // buf0 landed
  __builtin_amdgcn_s_barrier();
  __builtin_amdgcn_sched_barrier(0);

  f32x4 acc[4][4] = {};
  const int frow = lane & 15;
  const int fk   = (lane >> 4) * 8;

  for (int t = 0; t < nt; ++t) {
    const _Float16* sa = sA[t % 3];
    const _Float16* sb = sB[t % 3];
    if (t + 2 < nt)
      stage_tile(A, B, sA[(t + 2) % 3], sB[(t + 2) % 3], rowA, rowB,
                 (t + 2) * BK, K, wave, lane);

    f16x8 af[4][2], bf[4][2];
    #pragma unroll
    for (int m = 0; m < 4; ++m)
      #pragma unroll
      for (int kk = 0; kk < 2; ++kk)
        af[m][kk] = *(const f16x8*)&sa[(wr * 64 + m * 16 + frow) * BK + kk * 32 + fk];
    #pragma unroll
    for (int n = 0; n < 4; ++n)
      #pragma unroll
      for (int kk = 0; kk < 2; ++kk)
        bf[n][kk] = *(const f16x8*)&sb[(wc * 64 + n * 16 + frow) * BK + kk * 32 + fk];

    __builtin_amdgcn_s_setprio(1);
    #pragma unroll
    for (int kk = 0; kk < 2; ++kk)
      #pragma unroll
      for (int m = 0; m < 4; ++m)
        #pragma unroll
        for (int n = 0; n < 4; ++n)
          acc[m][n] = __builtin_amdgcn_mfma_f32_16x16x32_f16(af[m][kk], bf[n][kk], acc[m][n], 0, 0, 0);
    __builtin_amdgcn_s_setprio(0);

    if (t + 2 < nt) { asm volatile("s_waitcnt vmcnt(6)" ::: "memory"); }
    else            { asm volatile("s_waitcnt vmcnt(0)" ::: "memory"); }
    __builtin_amdgcn_s_barrier();
    __builtin_amdgcn_sched_barrier(0);
  }

  // ---------------- epilogue ----------------
  const int crow0 = (lane >> 4) * 4;
  const int ccol  = lane & 15;

  float bn[4], spn[4];
  if (MODE == 2 || MODE == 3) {
    #pragma unroll
    for (int n = 0; n < 4; ++n) {
      long c = rowB + wc * 64 + n * 16 + ccol;
      bn[n] = bias[c];
      if (MODE == 2) spn[n] = 8.f * log1pf(__expf(fl[c]));
    }
  }

  #pragma unroll
  for (int m = 0; m < 4; ++m)
    #pragma unroll
    for (int n = 0; n < 4; ++n) {
      long r0 = rowA + wr * 64 + m * 16 + crow0;
      long c  = rowB + wc * 64 + n * 16 + ccol;
      #pragma unroll
      for (int r = 0; r < 4; ++r) {
        float v = acc[m][n][r];
        long rr = r0 + r;
        if (MODE == 1) {
          if (c < HID) {
            float ge = 0.5f * v * (1.f + fast_erf(v * 0.70710678118654752f));
            Ch[rr * (long)HID + c] = (_Float16)ge;
          } else {
            Ch2[rr * (long)HID + (c - HID)] = (_Float16)v;
          }
        } else if (MODE == 2) {
          float rec = fast_sigmoid(v + bn[n]);
          Ch[rr * (long)N + c] = (_Float16)(spn[n] * rec);
        } else if (MODE == 3) {
          long idx = rr * (long)N + c;
          float inp  = fast_sigmoid(v + bn[n]);
          float a    = __expf(-(float)Sin[idx]);
          float beta = sqrtf(1.f - a * a + 1e-6f);
          Ch[idx] = (_Float16)(beta * inp * (float)xc_in[idx]);
        } else {
          Cf[rr * (long)N + c] = v;
        }
      }
    }
}

// ---------------- depthwise causal conv K=4, 8 channels/thread ---------
__global__ void k_conv(const _Float16* __restrict__ xhb, const float* __restrict__ cw,
                       const float* __restrict__ cb, _Float16* __restrict__ xch) {
  long i = (long)blockIdx.x * blockDim.x + threadIdx.x;   // over MM*HID/8
  if (i >= (long)MM * (HID / 8)) return;
  const int hb = (int)(i % (HID / 8));
  const long m = i / (HID / 8);
  const int t = (int)(m % TT);
  const int h0 = hb * 8;
  float acc[8];
  #pragma unroll
  for (int j = 0; j < 8; ++j) acc[j] = cb[h0 + j];
  #pragma unroll
  for (int k = 0; k < 4; ++k) {
    if (t + k - 3 >= 0) {
      f16x8 v = *(const f16x8*)&xhb[(m + k - 3) * (long)HID + h0];
      #pragma unroll
      for (int j = 0; j < 8; ++j) acc[j] += (float)v[j] * cw[(h0 + j) * 4 + k];
    }
  }
  f16x8 o;
  #pragma unroll
  for (int j = 0; j < 8; ++j) o[j] = (_Float16)acc[j];
  *(f16x8*)&xch[m * (long)HID + h0] = o;
}

// ---------------- scan phase 1: per-chunk aggregates -------------------
__global__ void k_scan1(const _Float16* __restrict__ sbuf, const _Float16* __restrict__ xbeta,
                        float* __restrict__ Ac, float* __restrict__ Bc) {
  long i = (long)blockIdx.x * blockDim.x + threadIdx.x;   // over BB*NC*HID
  if (i >= (long)BB * NC * HID) return;
  const int h = (int)(i % HID);
  const long bc = i / HID;
  const int c = (int)(bc % NC);
  const int b = (int)(bc / NC);
  const long base = ((long)b * TT + (long)c * CH) * HID + h;
  float A = 1.f, Bv = 0.f;
  for (int t = 0; t < CH; ++t) {
    float a = __expf(-(float)sbuf[base + (long)t * HID]);
    float x = (float)xbeta[base + (long)t * HID];
    A *= a;
    Bv = a * Bv + x;
  }
  Ac[i] = A; Bc[i] = Bv;
}

// ---------------- scan phase 2: prefix over chunks ---------------------
__global__ void k_scan2(const float* __restrict__ Ac, const float* __restrict__ Bc,
                        float* __restrict__ carry) {
  int i = blockIdx.x * blockDim.x + threadIdx.x;          // over BB*HID
  if (i >= BB * HID) return;
  const int h = i % HID;
  const int b = i / HID;
  float cv = 0.f;
  for (int c = 0; c < NC; ++c) {
    long idx = ((long)b * NC + c) * HID + h;
    carry[idx] = cv;
    cv = Ac[idx] * cv + Bc[idx];
  }
}

// -------- scan phase 3 fused with gelu-gate multiply: vb = geluG * h ----
__global__ void k_scan3(const _Float16* __restrict__ sbuf, const _Float16* __restrict__ xbeta,
                        const float* __restrict__ carry, const _Float16* __restrict__ geluG,
                        _Float16* __restrict__ vb) {
  long i = (long)blockIdx.x * blockDim.x + threadIdx.x;   // over BB*NC*HID
  if (i >= (long)BB * NC * HID) return;
  const int h = (int)(i % HID);
  const long bc = i / HID;
  const int c = (int)(bc % NC);
  const int b = (int)(bc / NC);
  const long base = ((long)b * TT + (long)c * CH) * HID + h;
  float hv = carry[i];
  for (int t = 0; t < CH; ++t) {
    long idx = base + (long)t * HID;
    float a = __expf(-(float)sbuf[idx]);
    hv = a * hv + (float)xbeta[idx];
    vb[idx] = (_Float16)((float)geluG[idx] * hv);
  }
}

extern "C" void kernel_launch(void* const* d_in, const int* in_sizes, int n_in,
                              void* d_out, int out_size, void* d_ws, size_t ws_size,
                              hipStream_t stream) {
  const float* x      = (const float*)d_in[0];
  const float* proj_w = (const float*)d_in[1];
  const float* conv_w = (const float*)d_in[2];
  const float* conv_b = (const float*)d_in[3];
  const float* ip_w   = (const float*)d_in[4];
  const float* ip_b   = (const float*)d_in[5];
  const float* gp_w   = (const float*)d_in[6];
  const float* gp_b   = (const float*)d_in[7];
  const float* fl     = (const float*)d_in[8];
  const float* out_w  = (const float*)d_in[9];
  float* out = (float*)d_out;
  (void)in_sizes; (void)n_in; (void)out_size;

  // ---- workspace layout (~134 MB) ----
  const size_t SZ_W    = (size_t)NPROJ * DIMX * 2;        //  6 MB weight buf (reused)
  const size_t SZ_MH16 = (size_t)MM * HID * 2;            // 32 MB
  const size_t NEED = SZ_W + 4 * SZ_MH16;
  if (ws_size < NEED) return;

  char* ws = (char*)d_ws;
  _Float16* wbuf  = (_Float16*)(ws);                       // weights (sequential reuse)
  _Float16* geluG = (_Float16*)(ws + SZ_W);                // gelu(gate) fp16
  _Float16* xhb   = (_Float16*)(ws + SZ_W + SZ_MH16);      // xh fp16 -> later xbeta fp16
  _Float16* xch   = (_Float16*)(ws + SZ_W + 2 * SZ_MH16);  // conv out fp16 -> later vb
  _Float16* sbuf  = (_Float16*)(ws + SZ_W + 3 * SZ_MH16);  // s = 8*softplus*rec (fp16)

  // d_out aliasing: fp16 x (32MB) + scan temps (4.5MB); GEMM4 overwrites at end
  _Float16* xb    = (_Float16*)d_out;                      // 33,554,432 B
  float*    Ac    = (float*)((char*)d_out + 33554432);
  float*    Bc    = (float*)((char*)d_out + 35127296);
  float*    carry = (float*)((char*)d_out + 36700160);     // ends < 64 MB

  const int THR = 256;
  auto blocks = [&](long n) { return dim3((unsigned)((n + THR - 1) / THR)); };

  // x -> fp16 (into d_out)
  k_cvt<<<blocks((long)MM * DIMX / 4), THR, 0, stream>>>(x, xb, (long)MM * DIMX / 4);

  // GEMM1: [M,3072] = xb @ proj_w^T ; epilogue: gelu(gate) / raw xh split
  k_cvt<<<blocks((long)NPROJ * DIMX / 4), THR, 0, stream>>>(proj_w, wbuf, (long)NPROJ * DIMX / 4);
  k_gemm<1><<<dim3((MM / BM) * (NPROJ / BN)), 512, 0, stream>>>(
      xb, wbuf, nullptr, geluG, xhb, nullptr, nullptr, nullptr, nullptr,
      MM, NPROJ, DIMX, NPROJ / BN);

  // conv: xhb -> xch (fp16)
  k_conv<<<blocks((long)MM * (HID / 8)), THR, 0, stream>>>(xhb, conv_w, conv_b, xch);

  // GEMM2: s = 8*softplus(fl)*sigmoid(xch@gp_w^T + gp_b)  -> fp16 sbuf
  k_cvt<<<blocks((long)HID * HID / 4), THR, 0, stream>>>(gp_w, wbuf, (long)HID * HID / 4);
  k_gemm<2><<<dim3((MM / BM) * (HID / BN)), 512, 0, stream>>>(
      xch, wbuf, nullptr, sbuf, nullptr, gp_b, fl, nullptr, nullptr,
      MM, HID, HID, HID / BN);

  // GEMM3: xbeta = beta*sigmoid(xch@ip_w^T + ip_b)*xc -> fp16 into xhb
  k_cvt<<<blocks((long)HID * HID / 4), THR, 0, stream>>>(ip_w, wbuf, (long)HID * HID / 4);
  k_gemm<3><<<dim3((MM / BM) * (HID / BN)), 512, 0, stream>>>(
      xch, wbuf, nullptr, xhb, nullptr, ip_b, nullptr, sbuf, xch,
      MM, HID, HID, HID / BN);

  // scan (h never materialized in fp32: phase 3 fuses gelu-gate multiply)
  k_scan1<<<blocks((long)BB * NC * HID), THR, 0, stream>>>(sbuf, xhb, Ac, Bc);
  k_scan2<<<blocks(BB * HID), THR, 0, stream>>>(Ac, Bc, carry);
  k_scan3<<<blocks((long)BB * NC * HID), THR, 0, stream>>>(sbuf, xhb, carry, geluG, xch);

  // GEMM4: out = vb @ out_w^T (plain fp32)
  k_cvt<<<blocks((long)DIMX * HID / 4), THR, 0, stream>>>(out_w, wbuf, (long)DIMX * HID / 4);
  k_gemm<4><<<dim3((MM / BM) * (DIMX / BN)), 512, 0, stream>>>(
      xch, wbuf, out, nullptr, nullptr, nullptr, nullptr, nullptr, nullptr,
      MM, DIMX, HID, DIMX / BN);
}

// Round 4
// 761.126 us; speedup vs baseline: 1.3339x; 1.2020x over previous
//
#include <hip/hip_runtime.h>
#include <cstdint>
#include <cstddef>

#define DIMX 1024
#define HID  1536
#define BB   4
#define TT   4096
#define MM   (BB*TT)       // 16384 rows
#define NPROJ (2*HID)      // 3072
#define NC   64            // scan chunks
#define CH   64            // chunk length (NC*CH == TT)

typedef _Float16 f16x8 __attribute__((ext_vector_type(8)));
typedef float    f32x4 __attribute__((ext_vector_type(4)));

#define GLOAD_LDS16(g, l) \
  __builtin_amdgcn_global_load_lds((__attribute__((address_space(1))) const void*)(g), \
                                   (__attribute__((address_space(3))) void*)(l), 16, 0, 0)

__device__ __forceinline__ float fast_sigmoid(float z) {
  return 1.f / (1.f + __expf(-z));
}
__device__ __forceinline__ float fast_erf(float x) {
  float ax = fabsf(x);
  float t = 1.f / (1.f + 0.3275911f * ax);
  float p = t * (0.254829592f + t * (-0.284496736f + t * (1.421413741f +
            t * (-1.453152027f + t * 1.061405429f))));
  float r = 1.f - p * __expf(-ax * ax);
  return copysignf(r, x);
}

// ---------------- convert fp32 -> fp16, 4 elems/thread ----------------
__global__ void k_cvt(const float* __restrict__ in, _Float16* __restrict__ out, long n4) {
  long i = (long)blockIdx.x * blockDim.x + threadIdx.x;
  if (i >= n4) return;
  float4 v = ((const float4*)in)[i];
  union { _Float16 h[4]; uint64_t u; } r;
  r.h[0] = (_Float16)v.x; r.h[1] = (_Float16)v.y;
  r.h[2] = (_Float16)v.z; r.h[3] = (_Float16)v.w;
  ((uint64_t*)out)[i] = r.u;
}

// ---------------- GEMM: C[M,N] = A[M,K] * B[N,K]^T, fp16 in ----------
// 128x256 tile, BK=64, 8 waves (2M x 4N), wave = 64x64 out (4x4 frags).
// Triple-buffered LDS, 2-deep global_load_lds prefetch, counted vmcnt(6),
// raw s_barrier (1 per K-tile), setprio around MFMA, XCD swizzle.
// T2 LDS XOR-swizzle: linear LDS dest (global_load_lds requirement),
// inverse-swizzled GLOBAL source, swizzled ds_read address (rule #21).
// Row r of a tile lives at byte r*128; 16B-granule g of row r is stored at
// physical granule g ^ (r&7)  ->  stride-128B reads spread across all banks.
// MODE 1: col<HID -> gelu -> Ch[M,HID]; col>=HID -> raw fp16 -> Ch2[M,HID]
// MODE 2: s = 8*softplus(fl[c])*sigmoid(v+bias[c]) -> Ch fp16 [M,N]
// MODE 3: xbeta = sqrt(1-a^2+1e-6)*sigmoid(v+bias[c])*xc, a=exp(-s) -> Ch fp16
// MODE 4: plain fp32 -> Cf
#define BM 128
#define BN 256
#define BK 64

__device__ __forceinline__ void stage_tile(
    const _Float16* __restrict__ A, const _Float16* __restrict__ B,
    _Float16* sAbuf, _Float16* sBbuf,
    long rowA, long rowB, int kt, int K, int wave, int lane)
{
  const int r8  = lane >> 3;                    // row within 8-row chunk
  const int gsw = ((lane & 7) ^ r8) * 8;        // inverse-swizzled col granule
  #pragma unroll
  for (int j = 0; j < 2; ++j) {
    const int ck = wave + 8 * j;       // A chunks 0..15 (8 rows each)
    const _Float16* g = A + (rowA + ck * 8 + r8) * (long)K + kt + gsw;
    GLOAD_LDS16(g, sAbuf + ck * 512);
  }
  #pragma unroll
  for (int j = 0; j < 4; ++j) {
    const int ck = wave + 8 * j;       // B chunks 0..31
    const _Float16* g = B + (rowB + ck * 8 + r8) * (long)K + kt + gsw;
    GLOAD_LDS16(g, sBbuf + ck * 512);
  }
}

template<int MODE>
__global__ __launch_bounds__(512) void k_gemm(
    const _Float16* __restrict__ A, const _Float16* __restrict__ B,
    float* __restrict__ Cf, _Float16* __restrict__ Ch, _Float16* __restrict__ Ch2,
    const float* __restrict__ bias, const float* __restrict__ fl,
    const _Float16* __restrict__ Sin, const _Float16* __restrict__ xc_in,
    int M, int N, int K, int gridN)
{
  __shared__ __align__(16) _Float16 sA[3][BM * BK];   // 3 x 16 KB
  __shared__ __align__(16) _Float16 sB[3][BN * BK];   // 3 x 32 KB  (total 144 KB)
  const int tid  = threadIdx.x;
  const int wave = tid >> 6;
  const int lane = tid & 63;
  const int wr = wave >> 2, wc = wave & 3;

  // bijective XCD swizzle (gridDim.x % 8 == 0 for all our shapes)
  const int nwg = gridDim.x;
  const int bid = blockIdx.x;
  const int swz = (bid & 7) * (nwg >> 3) + (bid >> 3);
  const long rowA = (long)(swz / gridN) * BM;
  const long rowB = (long)(swz % gridN) * BN;

  const int nt = K / BK;

  stage_tile(A, B, sA[0], sB[0], rowA, rowB, 0,  K, wave, lane);
  stage_tile(A, B, sA[1], sB[1], rowA, rowB, BK, K, wave, lane);
  asm volatile("s_waitcnt vmcnt(6)" ::: "memory");   // buf0 landed
  __builtin_amdgcn_s_barrier();
  __builtin_amdgcn_sched_barrier(0);

  f32x4 acc[4][4] = {};
  const int frow = lane & 15;
  // T2 swizzled read granules (bytes): physical = (kk*4 + q) ^ (frow&7)
  const int pg0 = ((lane >> 4) ^ (frow & 7)) << 4;   // kk=0
  const int pg1 = pg0 ^ 64;                          // kk=1 (flips bit2 of granule)

  for (int t = 0; t < nt; ++t) {
    const char* sa = (const char*)sA[t % 3];
    const char* sb = (const char*)sB[t % 3];
    if (t + 2 < nt)
      stage_tile(A, B, sA[(t + 2) % 3], sB[(t + 2) % 3], rowA, rowB,
                 (t + 2) * BK, K, wave, lane);

    f16x8 af[4][2], bf[4][2];
    #pragma unroll
    for (int m = 0; m < 4; ++m) {
      const int rb = (wr * 64 + m * 16 + frow) * 128;
      af[m][0] = *(const f16x8*)(sa + rb + pg0);
      af[m][1] = *(const f16x8*)(sa + rb + pg1);
    }
    #pragma unroll
    for (int n = 0; n < 4; ++n) {
      const int rb = (wc * 64 + n * 16 + frow) * 128;
      bf[n][0] = *(const f16x8*)(sb + rb + pg0);
      bf[n][1] = *(const f16x8*)(sb + rb + pg1);
    }

    __builtin_amdgcn_s_setprio(1);
    #pragma unroll
    for (int kk = 0; kk < 2; ++kk)
      #pragma unroll
      for (int m = 0; m < 4; ++m)
        #pragma unroll
        for (int n = 0; n < 4; ++n)
          acc[m][n] = __builtin_amdgcn_mfma_f32_16x16x32_f16(af[m][kk], bf[n][kk], acc[m][n], 0, 0, 0);
    __builtin_amdgcn_s_setprio(0);

    if (t + 2 < nt) { asm volatile("s_waitcnt vmcnt(6)" ::: "memory"); }
    else            { asm volatile("s_waitcnt vmcnt(0)" ::: "memory"); }
    __builtin_amdgcn_s_barrier();
    __builtin_amdgcn_sched_barrier(0);
  }

  // ---------------- epilogue ----------------
  const int crow0 = (lane >> 4) * 4;
  const int ccol  = lane & 15;

  float bn[4], spn[4];
  if (MODE == 2 || MODE == 3) {
    #pragma unroll
    for (int n = 0; n < 4; ++n) {
      long c = rowB + wc * 64 + n * 16 + ccol;
      bn[n] = bias[c];
      if (MODE == 2) spn[n] = 8.f * log1pf(__expf(fl[c]));
    }
  }

  #pragma unroll
  for (int m = 0; m < 4; ++m)
    #pragma unroll
    for (int n = 0; n < 4; ++n) {
      long r0 = rowA + wr * 64 + m * 16 + crow0;
      long c  = rowB + wc * 64 + n * 16 + ccol;
      #pragma unroll
      for (int r = 0; r < 4; ++r) {
        float v = acc[m][n][r];
        long rr = r0 + r;
        if (MODE == 1) {
          if (c < HID) {
            float ge = 0.5f * v * (1.f + fast_erf(v * 0.70710678118654752f));
            Ch[rr * (long)HID + c] = (_Float16)ge;
          } else {
            Ch2[rr * (long)HID + (c - HID)] = (_Float16)v;
          }
        } else if (MODE == 2) {
          float rec = fast_sigmoid(v + bn[n]);
          Ch[rr * (long)N + c] = (_Float16)(spn[n] * rec);
        } else if (MODE == 3) {
          long idx = rr * (long)N + c;
          float inp  = fast_sigmoid(v + bn[n]);
          float a    = __expf(-(float)Sin[idx]);
          float beta = sqrtf(1.f - a * a + 1e-6f);
          Ch[idx] = (_Float16)(beta * inp * (float)xc_in[idx]);
        } else {
          Cf[rr * (long)N + c] = v;
        }
      }
    }
}

// ---------------- depthwise causal conv K=4, 8 channels/thread ---------
__global__ void k_conv(const _Float16* __restrict__ xhb, const float* __restrict__ cw,
                       const float* __restrict__ cb, _Float16* __restrict__ xch) {
  long i = (long)blockIdx.x * blockDim.x + threadIdx.x;   // over MM*HID/8
  if (i >= (long)MM * (HID / 8)) return;
  const int hb = (int)(i % (HID / 8));
  const long m = i / (HID / 8);
  const int t = (int)(m % TT);
  const int h0 = hb * 8;
  float acc[8];
  #pragma unroll
  for (int j = 0; j < 8; ++j) acc[j] = cb[h0 + j];
  #pragma unroll
  for (int k = 0; k < 4; ++k) {
    if (t + k - 3 >= 0) {
      f16x8 v = *(const f16x8*)&xhb[(m + k - 3) * (long)HID + h0];
      #pragma unroll
      for (int j = 0; j < 8; ++j) acc[j] += (float)v[j] * cw[(h0 + j) * 4 + k];
    }
  }
  f16x8 o;
  #pragma unroll
  for (int j = 0; j < 8; ++j) o[j] = (_Float16)acc[j];
  *(f16x8*)&xch[m * (long)HID + h0] = o;
}

// ---------------- scan phase 1: per-chunk aggregates -------------------
__global__ void k_scan1(const _Float16* __restrict__ sbuf, const _Float16* __restrict__ xbeta,
                        float* __restrict__ Ac, float* __restrict__ Bc) {
  long i = (long)blockIdx.x * blockDim.x + threadIdx.x;   // over BB*NC*HID
  if (i >= (long)BB * NC * HID) return;
  const int h = (int)(i % HID);
  const long bc = i / HID;
  const int c = (int)(bc % NC);
  const int b = (int)(bc / NC);
  const long base = ((long)b * TT + (long)c * CH) * HID + h;
  float A = 1.f, Bv = 0.f;
  for (int t = 0; t < CH; ++t) {
    float a = __expf(-(float)sbuf[base + (long)t * HID]);
    float x = (float)xbeta[base + (long)t * HID];
    A *= a;
    Bv = a * Bv + x;
  }
  Ac[i] = A; Bc[i] = Bv;
}

// ---------------- scan phase 2: prefix over chunks ---------------------
__global__ void k_scan2(const float* __restrict__ Ac, const float* __restrict__ Bc,
                        float* __restrict__ carry) {
  int i = blockIdx.x * blockDim.x + threadIdx.x;          // over BB*HID
  if (i >= BB * HID) return;
  const int h = i % HID;
  const int b = i / HID;
  float cv = 0.f;
  for (int c = 0; c < NC; ++c) {
    long idx = ((long)b * NC + c) * HID + h;
    carry[idx] = cv;
    cv = Ac[idx] * cv + Bc[idx];
  }
}

// -------- scan phase 3 fused with gelu-gate multiply: vb = geluG * h ----
__global__ void k_scan3(const _Float16* __restrict__ sbuf, const _Float16* __restrict__ xbeta,
                        const float* __restrict__ carry, const _Float16* __restrict__ geluG,
                        _Float16* __restrict__ vb) {
  long i = (long)blockIdx.x * blockDim.x + threadIdx.x;   // over BB*NC*HID
  if (i >= (long)BB * NC * HID) return;
  const int h = (int)(i % HID);
  const long bc = i / HID;
  const int c = (int)(bc % NC);
  const int b = (int)(bc / NC);
  const long base = ((long)b * TT + (long)c * CH) * HID + h;
  float hv = carry[i];
  for (int t = 0; t < CH; ++t) {
    long idx = base + (long)t * HID;
    float a = __expf(-(float)sbuf[idx]);
    hv = a * hv + (float)xbeta[idx];
    vb[idx] = (_Float16)((float)geluG[idx] * hv);
  }
}

extern "C" void kernel_launch(void* const* d_in, const int* in_sizes, int n_in,
                              void* d_out, int out_size, void* d_ws, size_t ws_size,
                              hipStream_t stream) {
  const float* x      = (const float*)d_in[0];
  const float* proj_w = (const float*)d_in[1];
  const float* conv_w = (const float*)d_in[2];
  const float* conv_b = (const float*)d_in[3];
  const float* ip_w   = (const float*)d_in[4];
  const float* ip_b   = (const float*)d_in[5];
  const float* gp_w   = (const float*)d_in[6];
  const float* gp_b   = (const float*)d_in[7];
  const float* fl     = (const float*)d_in[8];
  const float* out_w  = (const float*)d_in[9];
  float* out = (float*)d_out;
  (void)in_sizes; (void)n_in; (void)out_size;

  // ---- workspace layout (~134 MB) ----
  const size_t SZ_W    = (size_t)NPROJ * DIMX * 2;        //  6 MB weight buf (reused)
  const size_t SZ_MH16 = (size_t)MM * HID * 2;            // 32 MB
  const size_t NEED = SZ_W + 4 * SZ_MH16;
  if (ws_size < NEED) return;

  char* ws = (char*)d_ws;
  _Float16* wbuf  = (_Float16*)(ws);                       // weights (sequential reuse)
  _Float16* geluG = (_Float16*)(ws + SZ_W);                // gelu(gate) fp16
  _Float16* xhb   = (_Float16*)(ws + SZ_W + SZ_MH16);      // xh fp16 -> later xbeta fp16
  _Float16* xch   = (_Float16*)(ws + SZ_W + 2 * SZ_MH16);  // conv out fp16 -> later vb
  _Float16* sbuf  = (_Float16*)(ws + SZ_W + 3 * SZ_MH16);  // s = 8*softplus*rec (fp16)

  // d_out aliasing: fp16 x (32MB) + scan temps (4.5MB); GEMM4 overwrites at end
  _Float16* xb    = (_Float16*)d_out;                      // 33,554,432 B
  float*    Ac    = (float*)((char*)d_out + 33554432);
  float*    Bc    = (float*)((char*)d_out + 35127296);
  float*    carry = (float*)((char*)d_out + 36700160);     // ends < 64 MB

  const int THR = 256;
  auto blocks = [&](long n) { return dim3((unsigned)((n + THR - 1) / THR)); };

  // x -> fp16 (into d_out)
  k_cvt<<<blocks((long)MM * DIMX / 4), THR, 0, stream>>>(x, xb, (long)MM * DIMX / 4);

  // GEMM1: [M,3072] = xb @ proj_w^T ; epilogue: gelu(gate) / raw xh split
  k_cvt<<<blocks((long)NPROJ * DIMX / 4), THR, 0, stream>>>(proj_w, wbuf, (long)NPROJ * DIMX / 4);
  k_gemm<1><<<dim3((MM / BM) * (NPROJ / BN)), 512, 0, stream>>>(
      xb, wbuf, nullptr, geluG, xhb, nullptr, nullptr, nullptr, nullptr,
      MM, NPROJ, DIMX, NPROJ / BN);

  // conv: xhb -> xch (fp16)
  k_conv<<<blocks((long)MM * (HID / 8)), THR, 0, stream>>>(xhb, conv_w, conv_b, xch);

  // GEMM2: s = 8*softplus(fl)*sigmoid(xch@gp_w^T + gp_b)  -> fp16 sbuf
  k_cvt<<<blocks((long)HID * HID / 4), THR, 0, stream>>>(gp_w, wbuf, (long)HID * HID / 4);
  k_gemm<2><<<dim3((MM / BM) * (HID / BN)), 512, 0, stream>>>(
      xch, wbuf, nullptr, sbuf, nullptr, gp_b, fl, nullptr, nullptr,
      MM, HID, HID, HID / BN);

  // GEMM3: xbeta = beta*sigmoid(xch@ip_w^T + ip_b)*xc -> fp16 into xhb
  k_cvt<<<blocks((long)HID * HID / 4), THR, 0, stream>>>(ip_w, wbuf, (long)HID * HID / 4);
  k_gemm<3><<<dim3((MM / BM) * (HID / BN)), 512, 0, stream>>>(
      xch, wbuf, nullptr, xhb, nullptr, ip_b, nullptr, sbuf, xch,
      MM, HID, HID, HID / BN);

  // scan (h never materialized in fp32: phase 3 fuses gelu-gate multiply)
  k_scan1<<<blocks((long)BB * NC * HID), THR, 0, stream>>>(sbuf, xhb, Ac, Bc);
  k_scan2<<<blocks(BB * HID), THR, 0, stream>>>(Ac, Bc, carry);
  k_scan3<<<blocks((long)BB * NC * HID), THR, 0, stream>>>(sbuf, xhb, carry, geluG, xch);

  // GEMM4: out = vb @ out_w^T (plain fp32)
  k_cvt<<<blocks((long)DIMX * HID / 4), THR, 0, stream>>>(out_w, wbuf, (long)DIMX * HID / 4);
  k_gemm<4><<<dim3((MM / BM) * (DIMX / BN)), 512, 0, stream>>>(
      xch, wbuf, out, nullptr, nullptr, nullptr, nullptr, nullptr, nullptr,
      MM, DIMX, HID, DIMX / BN);
}